// Round 2
// 1065.644 us; speedup vs baseline: 1.0005x; 1.0005x over previous
//
#include <hip/hip_runtime.h>

// Max pool 2x2 stride 2, NCHW fp32.
// In:  (32, 128, 224, 224)  Out: (32, 128, 112, 112)
//
// v2 (resubmit — round 1 failure was a container acquisition error, not the
// kernel): fully lane-dense memory access.
//   - v1: each thread read 8 consecutive floats per row via two float4 loads
//     -> per-lane address stride of 32 B -> each wave load spanned 2 KB at 50%
//     segment utilization (2x TA/L1 transactions per instruction).
//   - Now: one thread = one dense float4 per input row (lane i at base+16*i,
//     perfectly coalesced 1 KB/wave loads), horizontal max in-register,
//     dense float2 store (512 B/wave).
//   - Index math: rows 2h and 2h+1 are contiguous (448 floats), and
//     112 row-pairs * 448 = 50176 = one full plane, so
//     in_offset = rowpair*448 + chunk*4 with a single magic-div by 56.

#define CHUNKS_PER_ROWPAIR 56            // 224 floats / 4 per float4
#define ROW_FLOATS 224

__global__ __launch_bounds__(256) void pool2d_kernel(
    const float* __restrict__ in, float* __restrict__ out, int n_chunks) {
    int idx = blockIdx.x * blockDim.x + threadIdx.x;
    if (idx >= n_chunks) return;

    int rp = idx / CHUNKS_PER_ROWPAIR;        // row-pair id in [0, 32*128*112)
    int cg = idx - rp * CHUNKS_PER_ROWPAIR;   // float4 chunk within row [0, 56)

    const float* p = in + (size_t)rp * (2 * ROW_FLOATS) + (size_t)cg * 4;

    float4 r0 = *(const float4*)(p);               // row 2h, 4 consecutive cols
    float4 r1 = *(const float4*)(p + ROW_FLOATS);  // row 2h+1, same cols

    float2 o;
    o.x = fmaxf(fmaxf(r0.x, r0.y), fmaxf(r1.x, r1.y));
    o.y = fmaxf(fmaxf(r0.z, r0.w), fmaxf(r1.z, r1.w));

    *(float2*)(out + (size_t)idx * 2) = o;
}

extern "C" void kernel_launch(void* const* d_in, const int* in_sizes, int n_in,
                              void* d_out, int out_size, void* d_ws, size_t ws_size,
                              hipStream_t stream) {
    const float* x = (const float*)d_in[0];
    float* y = (float*)d_out;

    // total output floats = 32*128*112*112 = 51,380,224; one thread per 2:
    int n_chunks = out_size / 2;            // 25,690,112
    int block = 256;
    int grid = (n_chunks + block - 1) / block;  // 100,352
    pool2d_kernel<<<grid, block, 0, stream>>>(x, y, n_chunks);
}